// Round 4
// baseline (18305.460 us; speedup 1.0000x reference)
//
#include <hip/hip_runtime.h>
#include <math.h>

#define BATCH 256
#define HID   512
#define DIN   256
#define SEQ   512
#define HIST  2048
#define NBLK  128

typedef __attribute__((ext_vector_type(8))) short short8;   // 8 bf16 = 4 VGPR
typedef __attribute__((ext_vector_type(4))) float floatx4;
typedef __attribute__((ext_vector_type(8))) float floatx8;

__device__ __forceinline__ unsigned short f32_bf16_rtne(float f) {
    unsigned u = __builtin_bit_cast(unsigned, f);
    unsigned r = u + 0x7FFFu + ((u >> 16) & 1u);
    return (unsigned short)(r >> 16);
}
__device__ __forceinline__ float bf16_f32(unsigned short s) {
    unsigned u = ((unsigned)s) << 16;
    return __builtin_bit_cast(float, u);
}
__device__ __forceinline__ float sigmoidf_(float v) {
    return 1.0f / (1.0f + __expf(-v));
}

// Sense-reversing grid barrier, agent (device) scope.
// Spin is relaxed; the FINAL load that observes the new generation is
// acquire, so it synchronizes-with the releasing store by the last block.
__device__ __forceinline__ void grid_barrier(int* cnt, int* gen) {
    __syncthreads();
    if (threadIdx.x == 0) {
        const int g = __hip_atomic_load(gen, __ATOMIC_RELAXED, __HIP_MEMORY_SCOPE_AGENT);
        // ACQ_REL RMW releases this block's h-writes into the release sequence
        const int arrived =
            __hip_atomic_fetch_add(cnt, 1, __ATOMIC_ACQ_REL, __HIP_MEMORY_SCOPE_AGENT);
        if (arrived == NBLK - 1) {
            __hip_atomic_store(cnt, 0, __ATOMIC_RELAXED, __HIP_MEMORY_SCOPE_AGENT);
            __hip_atomic_store(gen, g + 1, __ATOMIC_RELEASE, __HIP_MEMORY_SCOPE_AGENT);
        } else {
            while (__hip_atomic_load(gen, __ATOMIC_RELAXED, __HIP_MEMORY_SCOPE_AGENT) == g) {
                __builtin_amdgcn_s_sleep(2);
            }
            (void)__hip_atomic_load(gen, __ATOMIC_ACQUIRE, __HIP_MEMORY_SCOPE_AGENT);
        }
    }
    __syncthreads();
}

// split fp32 -> (hi, lo) bf16 pair
__global__ __launch_bounds__(256) void split_kernel(
    const float* __restrict__ src, short* __restrict__ hi, short* __restrict__ lo, int n)
{
    int i = blockIdx.x * 256 + threadIdx.x;
    if (i < n) {
        float v = src[i];
        unsigned short h = f32_bf16_rtne(v);
        hi[i] = (short)h;
        lo[i] = (short)f32_bf16_rtne(v - bf16_f32(h));
    }
}

__global__ __launch_bounds__(256) void split_copy_kernel(
    const float* __restrict__ src, float* __restrict__ dst,
    short* __restrict__ hi, short* __restrict__ lo, int n)
{
    int i = blockIdx.x * 256 + threadIdx.x;
    if (i < n) {
        float v = src[i];
        dst[i] = v;
        unsigned short h = f32_bf16_rtne(v);
        hi[i] = (short)h;
        lo[i] = (short)f32_bf16_rtne(v - bf16_f32(h));
    }
}

// Persistent GRU: one launch, SEQ steps, hand-rolled grid barrier per step.
// 128 blocks = 8 batch-tiles(32) x 16 u-tiles(32), XCD-swizzled so the 16
// blocks on one XCD share 2 u-tiles (~600KB weights resident in that L2).
// Per block: 4 waves, wave = 16(batch) x 16(u) MFMA tile, split-bf16 hi/lo.
__global__ __launch_bounds__(256) void gru_persistent(
    const float* __restrict__ x,       // [SEQ][BATCH][DIN]
    float* __restrict__ h0f, float* __restrict__ h1f,
    short* __restrict__ hhi0, short* __restrict__ hlo0,
    short* __restrict__ hhi1, short* __restrict__ hlo1,
    const short* __restrict__ wih_hi, const short* __restrict__ wih_lo,
    const short* __restrict__ whh_hi, const short* __restrict__ whh_lo,
    int* __restrict__ bar_cnt, int* __restrict__ bar_gen)
{
    const int bid   = blockIdx.x;
    const int ublk  = (bid & 7) * 2 + ((bid >> 3) & 1);  // 0..15
    const int btile = bid >> 4;                           // 0..7
    const int tid  = threadIdx.x;
    const int w    = tid >> 6;
    const int lane = tid & 63;
    const int quad = lane >> 4;
    const int n16  = lane & 15;

    const int m0 = btile * 32 + (w & 1) * 16;
    const int u0 = ublk * 32 + (w >> 1) * 16;
    const int un = u0 + n16;

    // loop-invariant weight fragment pointers
    const short* iRH = wih_hi + (0 * HID + un) * DIN + quad * 8;
    const short* iRL = wih_lo + (0 * HID + un) * DIN + quad * 8;
    const short* iZH = wih_hi + (1 * HID + un) * DIN + quad * 8;
    const short* iZL = wih_lo + (1 * HID + un) * DIN + quad * 8;
    const short* iNH = wih_hi + (2 * HID + un) * DIN + quad * 8;
    const short* iNL = wih_lo + (2 * HID + un) * DIN + quad * 8;
    const short* hRH = whh_hi + (0 * HID + un) * HID + quad * 8;
    const short* hRL = whh_lo + (0 * HID + un) * HID + quad * 8;
    const short* hZH = whh_hi + (1 * HID + un) * HID + quad * 8;
    const short* hZL = whh_lo + (1 * HID + un) * HID + quad * 8;
    const short* hNH = whh_hi + (2 * HID + un) * HID + quad * 8;
    const short* hNL = whh_lo + (2 * HID + un) * HID + quad * 8;

    for (int t = 0; t < SEQ; ++t) {
        const int even = ((t & 1) == 0);
        const float* hsrcf = even ? h0f : h1f;
        float*       hdstf = even ? h1f : h0f;
        const short* shi   = even ? hhi0 : hhi1;
        const short* slo   = even ? hlo0 : hlo1;
        short*       dhi   = even ? hhi1 : hhi0;
        short*       dlo   = even ? hlo1 : hlo0;

        floatx4 aR  = {0.f, 0.f, 0.f, 0.f};
        floatx4 aZ  = {0.f, 0.f, 0.f, 0.f};
        floatx4 aNI = {0.f, 0.f, 0.f, 0.f};
        floatx4 aNH = {0.f, 0.f, 0.f, 0.f};

        // ---- x part: K = DIN, convert fp32 -> split bf16 in-register ----
        {
            const float* xp = x + (size_t)t * BATCH * DIN + (m0 + n16) * DIN + quad * 8;
            #pragma unroll
            for (int k0 = 0; k0 < DIN; k0 += 32) {
                const floatx8 av = *(const floatx8*)(xp + k0);
                short8 ah, al;
                #pragma unroll
                for (int j = 0; j < 8; ++j) {
                    const float v = av[j];
                    const unsigned short hb = f32_bf16_rtne(v);
                    ah[j] = (short)hb;
                    al[j] = (short)f32_bf16_rtne(v - bf16_f32(hb));
                }
                const short8 rH = *(const short8*)(iRH + k0);
                const short8 rL = *(const short8*)(iRL + k0);
                const short8 zH = *(const short8*)(iZH + k0);
                const short8 zL = *(const short8*)(iZL + k0);
                const short8 nH = *(const short8*)(iNH + k0);
                const short8 nL = *(const short8*)(iNL + k0);

                aR  = __builtin_amdgcn_mfma_f32_16x16x32_bf16(ah, rH, aR, 0, 0, 0);
                aZ  = __builtin_amdgcn_mfma_f32_16x16x32_bf16(ah, zH, aZ, 0, 0, 0);
                aNI = __builtin_amdgcn_mfma_f32_16x16x32_bf16(ah, nH, aNI, 0, 0, 0);
                aR  = __builtin_amdgcn_mfma_f32_16x16x32_bf16(al, rH, aR, 0, 0, 0);
                aZ  = __builtin_amdgcn_mfma_f32_16x16x32_bf16(al, zH, aZ, 0, 0, 0);
                aNI = __builtin_amdgcn_mfma_f32_16x16x32_bf16(al, nH, aNI, 0, 0, 0);
                aR  = __builtin_amdgcn_mfma_f32_16x16x32_bf16(ah, rL, aR, 0, 0, 0);
                aZ  = __builtin_amdgcn_mfma_f32_16x16x32_bf16(ah, zL, aZ, 0, 0, 0);
                aNI = __builtin_amdgcn_mfma_f32_16x16x32_bf16(ah, nL, aNI, 0, 0, 0);
            }
        }

        // ---- h part: K = HID ----
        {
            const short* hH = shi + (m0 + n16) * HID + quad * 8;
            const short* hL = slo + (m0 + n16) * HID + quad * 8;
            #pragma unroll 4
            for (int k0 = 0; k0 < HID; k0 += 32) {
                const short8 ah = *(const short8*)(hH + k0);
                const short8 al = *(const short8*)(hL + k0);
                const short8 rH = *(const short8*)(hRH + k0);
                const short8 rL = *(const short8*)(hRL + k0);
                const short8 zH = *(const short8*)(hZH + k0);
                const short8 zL = *(const short8*)(hZL + k0);
                const short8 nH = *(const short8*)(hNH + k0);
                const short8 nL = *(const short8*)(hNL + k0);

                aR  = __builtin_amdgcn_mfma_f32_16x16x32_bf16(ah, rH, aR, 0, 0, 0);
                aZ  = __builtin_amdgcn_mfma_f32_16x16x32_bf16(ah, zH, aZ, 0, 0, 0);
                aNH = __builtin_amdgcn_mfma_f32_16x16x32_bf16(ah, nH, aNH, 0, 0, 0);
                aR  = __builtin_amdgcn_mfma_f32_16x16x32_bf16(al, rH, aR, 0, 0, 0);
                aZ  = __builtin_amdgcn_mfma_f32_16x16x32_bf16(al, zH, aZ, 0, 0, 0);
                aNH = __builtin_amdgcn_mfma_f32_16x16x32_bf16(al, nH, aNH, 0, 0, 0);
                aR  = __builtin_amdgcn_mfma_f32_16x16x32_bf16(ah, rL, aR, 0, 0, 0);
                aZ  = __builtin_amdgcn_mfma_f32_16x16x32_bf16(ah, zL, aZ, 0, 0, 0);
                aNH = __builtin_amdgcn_mfma_f32_16x16x32_bf16(ah, nL, aNH, 0, 0, 0);
            }
        }

        // ---- epilogue: gates + h update ----
        #pragma unroll
        for (int rr = 0; rr < 4; ++rr) {
            const int b = m0 + quad * 4 + rr;
            const float r = sigmoidf_(aR[rr]);
            const float z = sigmoidf_(aZ[rr]);
            const float n = tanhf(aNI[rr] + r * aNH[rr]);
            const float hp = hsrcf[b * HID + un];
            const float hn = (1.0f - z) * n + z * hp;
            hdstf[b * HID + un] = hn;
            const unsigned short hb = f32_bf16_rtne(hn);
            dhi[b * HID + un] = (short)hb;
            dlo[b * HID + un] = (short)f32_bf16_rtne(hn - bf16_f32(hb));
        }

        grid_barrier(bar_cnt, bar_gen);
    }
}

// --- attention / sigma / mu ---
__global__ __launch_bounds__(256) void attn_kernel(
    const float* __restrict__ h,
    const float* __restrict__ external,
    const float* __restrict__ w_alpha,
    const float* __restrict__ w_sigma,
    float* __restrict__ mu,
    float* __restrict__ inv_sig,
    float* __restrict__ log_det)
{
    const int b = blockIdx.x;
    const int t = threadIdx.x;

    __shared__ float hs[HID];
    __shared__ float al[HIST];
    __shared__ float red[256];

    for (int k = t; k < HID; k += 256) hs[k] = h[(size_t)b * HID + k];
    __syncthreads();

    const float4* hs4 = (const float4*)hs;

    float lg[8];
    #pragma unroll
    for (int i = 0; i < 8; ++i) {
        const int e = t + 256 * i;
        const float4* wr = (const float4*)(w_alpha + (size_t)e * HID);
        float acc = 0.f;
        #pragma unroll 4
        for (int k = 0; k < HID / 4; ++k) {
            const float4 w4 = wr[k];
            const float4 h4 = hs4[k];
            acc += w4.x * h4.x + w4.y * h4.y + w4.z * h4.z + w4.w * h4.w;
        }
        lg[i] = acc;
    }

    float m = lg[0];
    #pragma unroll
    for (int i = 1; i < 8; ++i) m = fmaxf(m, lg[i]);
    red[t] = m;
    __syncthreads();
    for (int off = 128; off > 0; off >>= 1) {
        if (t < off) red[t] = fmaxf(red[t], red[t + off]);
        __syncthreads();
    }
    m = red[0];
    __syncthreads();

    float s = 0.f;
    #pragma unroll
    for (int i = 0; i < 8; ++i) {
        const float v = __expf(lg[i] - m);
        al[t + 256 * i] = v;
        s += v;
    }
    red[t] = s;
    __syncthreads();
    for (int off = 128; off > 0; off >>= 1) {
        if (t < off) red[t] += red[t + off];
        __syncthreads();
    }
    s = red[0];
    const float inv_s = 1.0f / s;
    __syncthreads();

    const int d = t;
    float acc_mu = 0.f;
    for (int e = 0; e < HIST; ++e) {
        acc_mu += al[e] * external[(size_t)e * DIN + d];
    }
    mu[(size_t)b * DIN + d] = acc_mu * inv_s;

    const float4* ws = (const float4*)(w_sigma + (size_t)d * HID);
    float sl = 0.f;
    #pragma unroll 4
    for (int k = 0; k < HID / 4; ++k) {
        const float4 w4 = ws[k];
        const float4 h4 = hs4[k];
        sl += w4.x * h4.x + w4.y * h4.y + w4.z * h4.z + w4.w * h4.w;
    }
    inv_sig[(size_t)b * DIN + d] = __expf(-sl);

    red[t] = sl;
    __syncthreads();
    for (int off = 128; off > 0; off >>= 1) {
        if (t < off) red[t] += red[t + off];
        __syncthreads();
    }
    if (t == 0) log_det[b] = red[0];
}

__global__ __launch_bounds__(256) void out_kernel(
    const float* __restrict__ x,
    const float* __restrict__ mu,
    const float* __restrict__ inv_sig,
    const float* __restrict__ log_det,
    float* __restrict__ out)
{
    const int s = blockIdx.x;
    const int b = threadIdx.x;
    const float4* xr = (const float4*)(x + ((size_t)s * BATCH + b) * DIN);
    const float4* mr = (const float4*)(mu + (size_t)b * DIN);
    const float4* ir = (const float4*)(inv_sig + (size_t)b * DIN);

    float maha = 0.f;
    #pragma unroll 8
    for (int k = 0; k < DIN / 4; ++k) {
        const float4 xv = xr[k];
        const float4 mv = mr[k];
        const float4 iv = ir[k];
        const float t0 = (xv.x - mv.x) * iv.x;
        const float t1 = (xv.y - mv.y) * iv.y;
        const float t2 = (xv.z - mv.z) * iv.z;
        const float t3 = (xv.w - mv.w) * iv.w;
        maha += t0 * t0 + t1 * t1 + t2 * t2 + t3 * t3;
    }
    const float LOG2PI = 1.8378770664093453f;
    out[(size_t)s * BATCH + b] = -0.5f * (maha + (float)DIN * LOG2PI) - log_det[b];
}

extern "C" void kernel_launch(void* const* d_in, const int* in_sizes, int n_in,
                              void* d_out, int out_size, void* d_ws, size_t ws_size,
                              hipStream_t stream)
{
    const float* x        = (const float*)d_in[0];
    const float* hidden   = (const float*)d_in[1];
    const float* external = (const float*)d_in[2];
    const float* w_ih     = (const float*)d_in[3];
    const float* w_hh     = (const float*)d_in[4];
    const float* w_alpha  = (const float*)d_in[5];
    const float* w_sigma  = (const float*)d_in[6];

    const int NH  = BATCH * HID;      // 131072
    const int NIH = 3 * HID * DIN;    // 393216
    const int NHH = 3 * HID * HID;    // 786432

    // ws layout: barrier words first (separate cachelines), then buffers
    char* p = (char*)d_ws;
    int*   bar_cnt = (int*)p;
    int*   bar_gen = (int*)(p + 64);
    p += 256;
    float* h0      = (float*)p; p += NH * 4;
    float* h1      = (float*)p; p += NH * 4;
    short* hhi0    = (short*)p; p += NH * 2;
    short* hlo0    = (short*)p; p += NH * 2;
    short* hhi1    = (short*)p; p += NH * 2;
    short* hlo1    = (short*)p; p += NH * 2;
    short* wih_hi  = (short*)p; p += NIH * 2;
    short* wih_lo  = (short*)p; p += NIH * 2;
    short* whh_hi  = (short*)p; p += NHH * 2;
    short* whh_lo  = (short*)p; p += NHH * 2;
    float* mu      = (float*)p; p += BATCH * DIN * 4;
    float* inv_sig = (float*)p; p += BATCH * DIN * 4;
    float* log_det = (float*)p; p += BATCH * 4;

    (void)hipMemsetAsync(d_ws, 0, 256, stream);  // zero barrier state (ws is poisoned)

    split_kernel<<<(NIH + 255) / 256, 256, 0, stream>>>(w_ih, wih_hi, wih_lo, NIH);
    split_kernel<<<(NHH + 255) / 256, 256, 0, stream>>>(w_hh, whh_hi, whh_lo, NHH);
    split_copy_kernel<<<(NH + 255) / 256, 256, 0, stream>>>(hidden, h0, hhi0, hlo0, NH);

    gru_persistent<<<dim3(NBLK), dim3(256), 0, stream>>>(
        x, h0, h1, hhi0, hlo0, hhi1, hlo1,
        wih_hi, wih_lo, whh_hi, whh_lo, bar_cnt, bar_gen);
    // SEQ even -> final hidden in h0

    attn_kernel<<<dim3(BATCH), dim3(256), 0, stream>>>(
        h0, external, w_alpha, w_sigma, mu, inv_sig, log_det);

    out_kernel<<<dim3(SEQ), dim3(256), 0, stream>>>(
        x, mu, inv_sig, log_det, (float*)d_out);
}

// Round 5
// 9242.398 us; speedup vs baseline: 1.9806x; 1.9806x over previous
//
#include <hip/hip_runtime.h>
#include <math.h>

#define BATCH 256
#define HID   512
#define DIN   256
#define SEQ   512
#define HIST  2048
#define NBLK  128   // 4 batch-groups x 32 u-tiles

typedef __attribute__((ext_vector_type(8))) short short8;   // 8 bf16 = 4 VGPR
typedef __attribute__((ext_vector_type(4))) float floatx4;
typedef __attribute__((ext_vector_type(8))) float floatx8;

__device__ __forceinline__ unsigned short f32_bf16_rtne(float f) {
    unsigned u = __builtin_bit_cast(unsigned, f);
    unsigned r = u + 0x7FFFu + ((u >> 16) & 1u);
    return (unsigned short)(r >> 16);
}
__device__ __forceinline__ float bf16_f32(unsigned short s) {
    unsigned u = ((unsigned)s) << 16;
    return __builtin_bit_cast(float, u);
}
__device__ __forceinline__ float sigmoidf_(float v) {
    return 1.0f / (1.0f + __expf(-v));
}

// split fp32 -> (hi, lo) bf16 pair
__global__ __launch_bounds__(256) void split_kernel(
    const float* __restrict__ src, short* __restrict__ hi, short* __restrict__ lo, int n)
{
    int i = blockIdx.x * 256 + threadIdx.x;
    if (i < n) {
        float v = src[i];
        unsigned short h = f32_bf16_rtne(v);
        hi[i] = (short)h;
        lo[i] = (short)f32_bf16_rtne(v - bf16_f32(h));
    }
}

__global__ __launch_bounds__(256) void split_copy_kernel(
    const float* __restrict__ src, float* __restrict__ dst,
    short* __restrict__ hi, short* __restrict__ lo, int n)
{
    int i = blockIdx.x * 256 + threadIdx.x;
    if (i < n) {
        float v = src[i];
        dst[i] = v;
        unsigned short h = f32_bf16_rtne(v);
        hi[i] = (short)h;
        lo[i] = (short)f32_bf16_rtne(v - bf16_f32(h));
    }
}

// Persistent GRU, weight-stationary in registers.
// Block bid: g = bid&3 (batch-group of 64), ut = bid>>2 (u-tile of 16).
// 8 waves split K = [x(256) | h(512)] into 96-wide slices; each wave holds
// its 3-gate hi/lo weight fragments (72 VGPRs) for the whole sequence.
// Sync: per-group (32 blocks) seq-number flags, release/acquire.
__global__ __launch_bounds__(512) void gru_persistent(
    const float* __restrict__ x,       // [SEQ][BATCH][DIN]
    float* __restrict__ h0f, float* __restrict__ h1f,
    short* __restrict__ hhi0, short* __restrict__ hlo0,
    short* __restrict__ hhi1, short* __restrict__ hlo1,
    const short* __restrict__ wih_hi, const short* __restrict__ wih_lo,
    const short* __restrict__ whh_hi, const short* __restrict__ whh_lo,
    int* __restrict__ flags)           // NBLK flags, 64B stride
{
    const int bid = blockIdx.x;
    const int g   = bid & 3;
    const int ut  = bid >> 2;
    const int tid = threadIdx.x;
    const int w    = tid >> 6;
    const int lane = tid & 63;
    const int quad = lane >> 4;
    const int n16  = lane & 15;

    const int u0    = ut * 16;
    const int mbase = g * 64;

    // ---- preload weight fragments (register-resident for all SEQ steps) ----
    short8 wfh[3][3], wfl[3][3];   // [gate][ktile]
    #pragma unroll
    for (int gt = 0; gt < 3; ++gt) {
        #pragma unroll
        for (int kt = 0; kt < 3; ++kt) {
            const int K0  = w * 96 + kt * 32;
            const int row = gt * HID + u0 + n16;
            if (K0 < DIN) {
                wfh[gt][kt] = *(const short8*)(wih_hi + row * DIN + K0 + quad * 8);
                wfl[gt][kt] = *(const short8*)(wih_lo + row * DIN + K0 + quad * 8);
            } else {
                wfh[gt][kt] = *(const short8*)(whh_hi + row * HID + (K0 - DIN) + quad * 8);
                wfl[gt][kt] = *(const short8*)(whh_lo + row * HID + (K0 - DIN) + quad * 8);
            }
        }
    }

    // K-split partial buffer: [pair][mt][acc(r,z,nI,nH)][row][col(+pad)]
    __shared__ float P[2][4][4][16][17];

    for (int t = 0; t < SEQ; ++t) {
        const int rb = t & 1;
        const short* RHi = rb ? hhi1 : hhi0;
        const short* RLo = rb ? hlo1 : hlo0;
        const float* RF  = rb ? h1f  : h0f;
        short* WHi = rb ? hhi0 : hhi1;
        short* WLo = rb ? hlo0 : hlo1;
        float* WF  = rb ? h0f  : h1f;

        // ---- wait for all blocks of this batch-group to finish step t-1 ----
        if (t > 0) {
            if (tid < 32) {
                const int fb = (tid * 4 + g) * 16;
                while (__hip_atomic_load(flags + fb, __ATOMIC_RELAXED,
                                         __HIP_MEMORY_SCOPE_AGENT) < t)
                    __builtin_amdgcn_s_sleep(1);
                (void)__hip_atomic_load(flags + fb, __ATOMIC_ACQUIRE,
                                        __HIP_MEMORY_SCOPE_AGENT);
            }
            __syncthreads();
        }

        floatx4 acc[4][4];
        #pragma unroll
        for (int mt = 0; mt < 4; ++mt)
            #pragma unroll
            for (int j = 0; j < 4; ++j)
                acc[mt][j] = (floatx4){0.f, 0.f, 0.f, 0.f};

        const float* xt = x + (size_t)t * BATCH * DIN;

#define MFMA9(AH, AL, KT, NIDX)                                                              \
    acc[mt][0]    = __builtin_amdgcn_mfma_f32_16x16x32_bf16(AH, wfh[0][KT], acc[mt][0], 0,0,0); \
    acc[mt][1]    = __builtin_amdgcn_mfma_f32_16x16x32_bf16(AH, wfh[1][KT], acc[mt][1], 0,0,0); \
    acc[mt][NIDX] = __builtin_amdgcn_mfma_f32_16x16x32_bf16(AH, wfh[2][KT], acc[mt][NIDX], 0,0,0); \
    acc[mt][0]    = __builtin_amdgcn_mfma_f32_16x16x32_bf16(AL, wfh[0][KT], acc[mt][0], 0,0,0); \
    acc[mt][1]    = __builtin_amdgcn_mfma_f32_16x16x32_bf16(AL, wfh[1][KT], acc[mt][1], 0,0,0); \
    acc[mt][NIDX] = __builtin_amdgcn_mfma_f32_16x16x32_bf16(AL, wfh[2][KT], acc[mt][NIDX], 0,0,0); \
    acc[mt][0]    = __builtin_amdgcn_mfma_f32_16x16x32_bf16(AH, wfl[0][KT], acc[mt][0], 0,0,0); \
    acc[mt][1]    = __builtin_amdgcn_mfma_f32_16x16x32_bf16(AH, wfl[1][KT], acc[mt][1], 0,0,0); \
    acc[mt][NIDX] = __builtin_amdgcn_mfma_f32_16x16x32_bf16(AH, wfl[2][KT], acc[mt][NIDX], 0,0,0);

        #pragma unroll
        for (int mt = 0; mt < 4; ++mt) {
            const int brow = mbase + mt * 16 + n16;
            #pragma unroll
            for (int kt = 0; kt < 3; ++kt) {
                const int K0 = w * 96 + kt * 32;
                if (K0 < DIN) {
                    const floatx8 xv = *(const floatx8*)(xt + brow * DIN + K0 + quad * 8);
                    short8 Ah, Al;
                    #pragma unroll
                    for (int j = 0; j < 8; ++j) {
                        const float v = xv[j];
                        const unsigned short hb = f32_bf16_rtne(v);
                        Ah[j] = (short)hb;
                        Al[j] = (short)f32_bf16_rtne(v - bf16_f32(hb));
                    }
                    MFMA9(Ah, Al, kt, 2)
                } else {
                    const short8 Ah = *(const short8*)(RHi + brow * HID + (K0 - DIN) + quad * 8);
                    const short8 Al = *(const short8*)(RLo + brow * HID + (K0 - DIN) + quad * 8);
                    MFMA9(Ah, Al, kt, 3)
                }
            }
        }
#undef MFMA9

        // ---- K-split reduction through LDS (4 pairwise phases) ----
        if (w < 2) {
            #pragma unroll
            for (int mt = 0; mt < 4; ++mt)
                #pragma unroll
                for (int j = 0; j < 4; ++j)
                    #pragma unroll
                    for (int rr = 0; rr < 4; ++rr)
                        P[w][mt][j][quad * 4 + rr][n16] = acc[mt][j][rr];
        }
        __syncthreads();
        if (w == 2 || w == 3) {
            const int s = w - 2;
            #pragma unroll
            for (int mt = 0; mt < 4; ++mt)
                #pragma unroll
                for (int j = 0; j < 4; ++j)
                    #pragma unroll
                    for (int rr = 0; rr < 4; ++rr)
                        P[s][mt][j][quad * 4 + rr][n16] += acc[mt][j][rr];
        }
        __syncthreads();
        if (w == 4 || w == 5) {
            const int s = w - 4;
            #pragma unroll
            for (int mt = 0; mt < 4; ++mt)
                #pragma unroll
                for (int j = 0; j < 4; ++j)
                    #pragma unroll
                    for (int rr = 0; rr < 4; ++rr)
                        P[s][mt][j][quad * 4 + rr][n16] += acc[mt][j][rr];
        }
        __syncthreads();
        if (w == 6 || w == 7) {
            const int s = w - 6;
            #pragma unroll
            for (int mt = 0; mt < 4; ++mt)
                #pragma unroll
                for (int j = 0; j < 4; ++j)
                    #pragma unroll
                    for (int rr = 0; rr < 4; ++rr)
                        P[s][mt][j][quad * 4 + rr][n16] += acc[mt][j][rr];
        }
        __syncthreads();

        // ---- epilogue: gates + h update (2 (b,u) pairs per thread) ----
        #pragma unroll
        for (int i = 0; i < 2; ++i) {
            const int p   = tid + i * 512;
            const int bl  = p >> 4;
            const int ul  = p & 15;
            const int mt  = bl >> 4;
            const int row = bl & 15;
            const float sR  = P[0][mt][0][row][ul] + P[1][mt][0][row][ul];
            const float sZ  = P[0][mt][1][row][ul] + P[1][mt][1][row][ul];
            const float sNI = P[0][mt][2][row][ul] + P[1][mt][2][row][ul];
            const float sNH = P[0][mt][3][row][ul] + P[1][mt][3][row][ul];
            const float r = sigmoidf_(sR);
            const float z = sigmoidf_(sZ);
            const float n = tanhf(sNI + r * sNH);
            const int b = mbase + bl;
            const int u = u0 + ul;
            const float hp = RF[b * HID + u];   // private to this block
            const float hn = (1.0f - z) * n + z * hp;
            WF[b * HID + u] = hn;
            const unsigned short hb = f32_bf16_rtne(hn);
            WHi[b * HID + u] = (short)hb;
            WLo[b * HID + u] = (short)f32_bf16_rtne(hn - bf16_f32(hb));
        }

        __syncthreads();   // drains each wave's vmcnt -> h writes are in L2
        if (tid == 0)
            __hip_atomic_store(flags + bid * 16, t + 1, __ATOMIC_RELEASE,
                               __HIP_MEMORY_SCOPE_AGENT);
    }
}

// --- attention / sigma / mu ---
__global__ __launch_bounds__(256) void attn_kernel(
    const float* __restrict__ h,
    const float* __restrict__ external,
    const float* __restrict__ w_alpha,
    const float* __restrict__ w_sigma,
    float* __restrict__ mu,
    float* __restrict__ inv_sig,
    float* __restrict__ log_det)
{
    const int b = blockIdx.x;
    const int t = threadIdx.x;

    __shared__ float hs[HID];
    __shared__ float al[HIST];
    __shared__ float red[256];

    for (int k = t; k < HID; k += 256) hs[k] = h[(size_t)b * HID + k];
    __syncthreads();

    const float4* hs4 = (const float4*)hs;

    float lg[8];
    #pragma unroll
    for (int i = 0; i < 8; ++i) {
        const int e = t + 256 * i;
        const float4* wr = (const float4*)(w_alpha + (size_t)e * HID);
        float acc = 0.f;
        #pragma unroll 4
        for (int k = 0; k < HID / 4; ++k) {
            const float4 w4 = wr[k];
            const float4 h4 = hs4[k];
            acc += w4.x * h4.x + w4.y * h4.y + w4.z * h4.z + w4.w * h4.w;
        }
        lg[i] = acc;
    }

    float m = lg[0];
    #pragma unroll
    for (int i = 1; i < 8; ++i) m = fmaxf(m, lg[i]);
    red[t] = m;
    __syncthreads();
    for (int off = 128; off > 0; off >>= 1) {
        if (t < off) red[t] = fmaxf(red[t], red[t + off]);
        __syncthreads();
    }
    m = red[0];
    __syncthreads();

    float s = 0.f;
    #pragma unroll
    for (int i = 0; i < 8; ++i) {
        const float v = __expf(lg[i] - m);
        al[t + 256 * i] = v;
        s += v;
    }
    red[t] = s;
    __syncthreads();
    for (int off = 128; off > 0; off >>= 1) {
        if (t < off) red[t] += red[t + off];
        __syncthreads();
    }
    s = red[0];
    const float inv_s = 1.0f / s;
    __syncthreads();

    const int d = t;
    float acc_mu = 0.f;
    for (int e = 0; e < HIST; ++e) {
        acc_mu += al[e] * external[(size_t)e * DIN + d];
    }
    mu[(size_t)b * DIN + d] = acc_mu * inv_s;

    const float4* ws = (const float4*)(w_sigma + (size_t)d * HID);
    float sl = 0.f;
    #pragma unroll 4
    for (int k = 0; k < HID / 4; ++k) {
        const float4 w4 = ws[k];
        const float4 h4 = hs4[k];
        sl += w4.x * h4.x + w4.y * h4.y + w4.z * h4.z + w4.w * h4.w;
    }
    inv_sig[(size_t)b * DIN + d] = __expf(-sl);

    red[t] = sl;
    __syncthreads();
    for (int off = 128; off > 0; off >>= 1) {
        if (t < off) red[t] += red[t + off];
        __syncthreads();
    }
    if (t == 0) log_det[b] = red[0];
}

__global__ __launch_bounds__(256) void out_kernel(
    const float* __restrict__ x,
    const float* __restrict__ mu,
    const float* __restrict__ inv_sig,
    const float* __restrict__ log_det,
    float* __restrict__ out)
{
    const int s = blockIdx.x;
    const int b = threadIdx.x;
    const float4* xr = (const float4*)(x + ((size_t)s * BATCH + b) * DIN);
    const float4* mr = (const float4*)(mu + (size_t)b * DIN);
    const float4* ir = (const float4*)(inv_sig + (size_t)b * DIN);

    float maha = 0.f;
    #pragma unroll 8
    for (int k = 0; k < DIN / 4; ++k) {
        const float4 xv = xr[k];
        const float4 mv = mr[k];
        const float4 iv = ir[k];
        const float t0 = (xv.x - mv.x) * iv.x;
        const float t1 = (xv.y - mv.y) * iv.y;
        const float t2 = (xv.z - mv.z) * iv.z;
        const float t3 = (xv.w - mv.w) * iv.w;
        maha += t0 * t0 + t1 * t1 + t2 * t2 + t3 * t3;
    }
    const float LOG2PI = 1.8378770664093453f;
    out[(size_t)s * BATCH + b] = -0.5f * (maha + (float)DIN * LOG2PI) - log_det[b];
}

extern "C" void kernel_launch(void* const* d_in, const int* in_sizes, int n_in,
                              void* d_out, int out_size, void* d_ws, size_t ws_size,
                              hipStream_t stream)
{
    const float* x        = (const float*)d_in[0];
    const float* hidden   = (const float*)d_in[1];
    const float* external = (const float*)d_in[2];
    const float* w_ih     = (const float*)d_in[3];
    const float* w_hh     = (const float*)d_in[4];
    const float* w_alpha  = (const float*)d_in[5];
    const float* w_sigma  = (const float*)d_in[6];

    const int NH  = BATCH * HID;      // 131072
    const int NIH = 3 * HID * DIN;    // 393216
    const int NHH = 3 * HID * HID;    // 786432

    // ws layout: flags first (NBLK x 64B), then buffers
    char* p = (char*)d_ws;
    int*   flags = (int*)p;
    p += NBLK * 64;
    float* h0      = (float*)p; p += NH * 4;
    float* h1      = (float*)p; p += NH * 4;
    short* hhi0    = (short*)p; p += NH * 2;
    short* hlo0    = (short*)p; p += NH * 2;
    short* hhi1    = (short*)p; p += NH * 2;
    short* hlo1    = (short*)p; p += NH * 2;
    short* wih_hi  = (short*)p; p += NIH * 2;
    short* wih_lo  = (short*)p; p += NIH * 2;
    short* whh_hi  = (short*)p; p += NHH * 2;
    short* whh_lo  = (short*)p; p += NHH * 2;
    float* mu      = (float*)p; p += BATCH * DIN * 4;
    float* inv_sig = (float*)p; p += BATCH * DIN * 4;
    float* log_det = (float*)p; p += BATCH * 4;

    (void)hipMemsetAsync(d_ws, 0, NBLK * 64, stream);  // zero flags every call

    split_kernel<<<(NIH + 255) / 256, 256, 0, stream>>>(w_ih, wih_hi, wih_lo, NIH);
    split_kernel<<<(NHH + 255) / 256, 256, 0, stream>>>(w_hh, whh_hi, whh_lo, NHH);
    split_copy_kernel<<<(NH + 255) / 256, 256, 0, stream>>>(hidden, h0, hhi0, hlo0, NH);

    gru_persistent<<<dim3(NBLK), dim3(512), 0, stream>>>(
        x, h0, h1, hhi0, hlo0, hhi1, hlo1,
        wih_hi, wih_lo, whh_hi, whh_lo, flags);
    // SEQ even -> final hidden in h0

    attn_kernel<<<dim3(BATCH), dim3(256), 0, stream>>>(
        h0, external, w_alpha, w_sigma, mu, inv_sig, log_det);

    out_kernel<<<dim3(SEQ), dim3(256), 0, stream>>>(
        x, mu, inv_sig, log_det, (float*)d_out);
}

// Round 6
// 4553.705 us; speedup vs baseline: 4.0199x; 2.0296x over previous
//
#include <hip/hip_runtime.h>
#include <math.h>

#define BATCH 256
#define HID   512
#define DIN   256
#define SEQ   512
#define HIST  2048
#define NBLK  256     // 8 batch-groups x 32 u-tiles
#define NGRP  8
#define GB    32      // batches per group

typedef __attribute__((ext_vector_type(8))) short short8;
typedef __attribute__((ext_vector_type(4))) float floatx4;
typedef __attribute__((ext_vector_type(8))) float floatx8;
typedef unsigned long long ull;
typedef unsigned int uint;

__device__ __forceinline__ unsigned short f32_bf16_rtne(float f) {
    uint u = __builtin_bit_cast(uint, f);
    uint r = u + 0x7FFFu + ((u >> 16) & 1u);
    return (unsigned short)(r >> 16);
}
__device__ __forceinline__ float bf16_f32(unsigned short s) {
    uint u = ((uint)s) << 16;
    return __builtin_bit_cast(float, u);
}
__device__ __forceinline__ float sigmoidf_(float v) {
    return 1.0f / (1.0f + __expf(-v));
}

// fragment-layout word index for packed h within one group's buffer:
// reader wave lane l=(quad,n16) for (K,mt) reads words ((K*2+mt)*64+l)*8 + j
__device__ __forceinline__ int h_widx(int b_local, int u) {
    return ((u >> 5) * 2 + (b_local >> 4)) * 512 +
           ((u >> 3) & 3) * 128 + (b_local & 15) * 8 + (u & 7);
}

// split fp32 -> (hi, lo) bf16 pair (weights)
__global__ __launch_bounds__(256) void split_kernel(
    const float* __restrict__ src, short* __restrict__ hi, short* __restrict__ lo, int n)
{
    int i = blockIdx.x * 256 + threadIdx.x;
    if (i < n) {
        float v = src[i];
        unsigned short h = f32_bf16_rtne(v);
        hi[i] = (short)h;
        lo[i] = (short)f32_bf16_rtne(v - bf16_f32(h));
    }
}

// initial hidden -> packed frag-layout buffer 0
__global__ __launch_bounds__(256) void pack_h_init(
    const float* __restrict__ hidden, uint* __restrict__ hp0)
{
    int i = blockIdx.x * 256 + threadIdx.x;   // 131072
    int b = i >> 9, u = i & 511;
    int g = b >> 5, bl = b & 31;
    float v = hidden[i];
    unsigned short hi = f32_bf16_rtne(v);
    unsigned short lo = f32_bf16_rtne(v - bf16_f32(hi));
    hp0[g * 16384 + h_widx(bl, u)] = (uint)hi | ((uint)lo << 16);
}

// Persistent GRU. 256 blocks x 512 thr (8 waves). Block (g = bid&7,
// ublk = bid>>3): 32 batches x 16 hidden units. Waves split K=[x 256|h 512]
// into 96-wide slices; weights register-resident (72 VGPR). h exchanged as
// packed (hi|lo) words via relaxed agent-scope atomics (LLC-coherent, no L2
// invalidates). Per-wave polling of the <=6 producer flags it depends on.
__global__ __launch_bounds__(512, 2) void gru_persistent(
    const float* __restrict__ x,        // [SEQ][BATCH][DIN]
    const float* __restrict__ hidden,   // [1][BATCH][HID]
    uint* __restrict__ hpA, uint* __restrict__ hpB,   // packed h ping-pong
    const short* __restrict__ wih_hi, const short* __restrict__ wih_lo,
    const short* __restrict__ whh_hi, const short* __restrict__ whh_lo,
    int* __restrict__ flags)            // NBLK flags, 64B stride
{
    const int bid  = blockIdx.x;
    const int g    = bid & 7;
    const int ublk = bid >> 3;
    const int u0   = ublk * 16;
    const int tid  = threadIdx.x;
    const int w    = tid >> 6;
    const int lane = tid & 63;
    const int quad = lane >> 4;
    const int n16  = lane & 15;
    const int mbase = g * GB;

    // ---- register-resident weight fragments: [gate][kt], hi+lo ----
    short8 Bh[3][3], Bl[3][3];
    #pragma unroll
    for (int gt = 0; gt < 3; ++gt) {
        #pragma unroll
        for (int kt = 0; kt < 3; ++kt) {
            const int K0  = w * 96 + kt * 32;
            const int row = gt * HID + u0 + n16;
            if (K0 < DIN) {
                Bh[gt][kt] = *(const short8*)(wih_hi + row * DIN + K0 + quad * 8);
                Bl[gt][kt] = *(const short8*)(wih_lo + row * DIN + K0 + quad * 8);
            } else {
                Bh[gt][kt] = *(const short8*)(whh_hi + row * HID + (K0 - DIN) + quad * 8);
                Bl[gt][kt] = *(const short8*)(whh_lo + row * HID + (K0 - DIN) + quad * 8);
            }
        }
    }

    // ---- this thread's output element: h_prev stays in a register ----
    const int ob = tid >> 4;          // b_local 0..31
    const int ou = tid & 15;          // u_local 0..15
    float hp = hidden[(mbase + ob) * HID + (u0 + ou)];
    const int my_widx = h_widx(ob, u0 + ou);

    // per-wave poll set: producer u-blocks covering this wave's h k-range
    const int pollCnt  = (w == 2) ? 2 : (w >= 3 ? 6 : 0);
    const int pollBase = (w <= 2) ? 0 : (w * 6 - 16);

    __shared__ float P[2][2][4][16][20];  // [region][mt][acc][u_col][b_row+pad]

    for (int t = 0; t < SEQ; ++t) {
        const uint* hsrc = (t & 1) ? hpB : hpA;
        uint*       hdst = (t & 1) ? hpA : hpB;

        floatx4 acc[2][4];
        #pragma unroll
        for (int mt = 0; mt < 2; ++mt)
            #pragma unroll
            for (int j = 0; j < 4; ++j)
                acc[mt][j] = (floatx4){0.f, 0.f, 0.f, 0.f};

#define MFMA3(AH, AL, BH, BL, ACC)                                        \
    ACC = __builtin_amdgcn_mfma_f32_16x16x32_bf16(AH, BH, ACC, 0, 0, 0);  \
    ACC = __builtin_amdgcn_mfma_f32_16x16x32_bf16(AL, BH, ACC, 0, 0, 0);  \
    ACC = __builtin_amdgcn_mfma_f32_16x16x32_bf16(AH, BL, ACC, 0, 0, 0);

        // ---- x part (pre-sync; independent of h) ----
        const float* xt = x + (size_t)t * BATCH * DIN;
        #pragma unroll
        for (int kt = 0; kt < 3; ++kt) {
            const int K0 = w * 96 + kt * 32;
            if (K0 < DIN) {
                #pragma unroll
                for (int mt = 0; mt < 2; ++mt) {
                    const int row = mbase + mt * 16 + n16;
                    const floatx8 xv = *(const floatx8*)(xt + row * DIN + K0 + quad * 8);
                    short8 Ah, Al;
                    #pragma unroll
                    for (int j = 0; j < 8; ++j) {
                        const float v = xv[j];
                        const unsigned short hb = f32_bf16_rtne(v);
                        Ah[j] = (short)hb;
                        Al[j] = (short)f32_bf16_rtne(v - bf16_f32(hb));
                    }
                    MFMA3(Ah, Al, Bh[0][kt], Bl[0][kt], acc[mt][0])
                    MFMA3(Ah, Al, Bh[1][kt], Bl[1][kt], acc[mt][1])
                    MFMA3(Ah, Al, Bh[2][kt], Bl[2][kt], acc[mt][2])
                }
            }
        }

        // ---- wait for this wave's producers (step t-1 done) ----
        if (lane < pollCnt) {
            const int fo = ((pollBase + lane) * 8 + g) * 16;
            while (__hip_atomic_load(flags + fo, __ATOMIC_RELAXED,
                                     __HIP_MEMORY_SCOPE_AGENT) < t)
                __builtin_amdgcn_s_sleep(2);
        }
        __builtin_amdgcn_sched_barrier(0);   // keep h loads after the poll

        // ---- h part: lane-contiguous relaxed-atomic b64 loads from LLC ----
        ull hv[3][2][4];
        const ull* hsrc8 = (const ull*)hsrc + (size_t)g * 8192;
        #pragma unroll
        for (int kt = 0; kt < 3; ++kt) {
            const int K0 = w * 96 + kt * 32;
            if (K0 >= DIN) {
                const int K = (K0 - DIN) >> 5;
                #pragma unroll
                for (int mt = 0; mt < 2; ++mt) {
                    const ull* base = hsrc8 + ((K * 2 + mt) * 64 + lane) * 4;
                    #pragma unroll
                    for (int j2 = 0; j2 < 4; ++j2)
                        hv[kt][mt][j2] = __hip_atomic_load(base + j2, __ATOMIC_RELAXED,
                                                           __HIP_MEMORY_SCOPE_AGENT);
                }
            }
        }
        #pragma unroll
        for (int kt = 0; kt < 3; ++kt) {
            const int K0 = w * 96 + kt * 32;
            if (K0 >= DIN) {
                #pragma unroll
                for (int mt = 0; mt < 2; ++mt) {
                    union { int i[8]; short8 s8[2]; } U;
                    #pragma unroll
                    for (int j2 = 0; j2 < 4; ++j2) {
                        const uint w0 = (uint)hv[kt][mt][j2];
                        const uint w1 = (uint)(hv[kt][mt][j2] >> 32);
                        U.i[j2]     = (int)((w0 & 0xFFFFu) | (w1 << 16));        // hi pair
                        U.i[4 + j2] = (int)((w0 >> 16) | (w1 & 0xFFFF0000u));    // lo pair
                    }
                    const short8 Ah = U.s8[0];
                    const short8 Al = U.s8[1];
                    MFMA3(Ah, Al, Bh[0][kt], Bl[0][kt], acc[mt][0])
                    MFMA3(Ah, Al, Bh[1][kt], Bl[1][kt], acc[mt][1])
                    MFMA3(Ah, Al, Bh[2][kt], Bl[2][kt], acc[mt][3])
                }
            }
        }
#undef MFMA3

        // ---- K-split reduction, vectorized b128, 20-float padded rows ----
        if (w < 2) {
            #pragma unroll
            for (int mt = 0; mt < 2; ++mt)
                #pragma unroll
                for (int a = 0; a < 4; ++a)
                    *(floatx4*)&P[w][mt][a][n16][quad * 4] = acc[mt][a];
        }
        __syncthreads();
        if (w == 2 || w == 3) {
            const int r = w - 2;
            #pragma unroll
            for (int mt = 0; mt < 2; ++mt)
                #pragma unroll
                for (int a = 0; a < 4; ++a) {
                    floatx4* p = (floatx4*)&P[r][mt][a][n16][quad * 4];
                    *p = *p + acc[mt][a];
                }
        }
        __syncthreads();
        if (w == 4 || w == 5) {
            const int r = w - 4;
            #pragma unroll
            for (int mt = 0; mt < 2; ++mt)
                #pragma unroll
                for (int a = 0; a < 4; ++a) {
                    floatx4* p = (floatx4*)&P[r][mt][a][n16][quad * 4];
                    *p = *p + acc[mt][a];
                }
        }
        __syncthreads();
        if (w == 6 || w == 7) {
            const int r = w - 6;
            #pragma unroll
            for (int mt = 0; mt < 2; ++mt)
                #pragma unroll
                for (int a = 0; a < 4; ++a) {
                    floatx4* p = (floatx4*)&P[r][mt][a][n16][quad * 4];
                    *p = *p + acc[mt][a];
                }
        }
        __syncthreads();

        // ---- epilogue: one (b,u) per thread; h_prev from register ----
        {
            const int mt = ob >> 4, rw = ob & 15;
            const float sR  = P[0][mt][0][ou][rw] + P[1][mt][0][ou][rw];
            const float sZ  = P[0][mt][1][ou][rw] + P[1][mt][1][ou][rw];
            const float sNI = P[0][mt][2][ou][rw] + P[1][mt][2][ou][rw];
            const float sNH = P[0][mt][3][ou][rw] + P[1][mt][3][ou][rw];
            const float r = sigmoidf_(sR);
            const float z = sigmoidf_(sZ);
            const float n = tanhf(sNI + r * sNH);
            const float hn = (1.0f - z) * n + z * hp;
            hp = hn;
            const unsigned short hb = f32_bf16_rtne(hn);
            const unsigned short lb = f32_bf16_rtne(hn - bf16_f32(hb));
            const uint word = (uint)hb | ((uint)lb << 16);
            __hip_atomic_store(hdst + (size_t)g * 16384 + my_widx, word,
                               __ATOMIC_RELAXED, __HIP_MEMORY_SCOPE_AGENT);
        }

        __syncthreads();   // every wave drains vmcnt -> all h words at LLC
        if (tid == 0)
            __hip_atomic_store(flags + bid * 16, t + 1, __ATOMIC_RELEASE,
                               __HIP_MEMORY_SCOPE_AGENT);
    }
}

// --- attention / sigma / mu (reads packed final h) ---
__global__ __launch_bounds__(256) void attn_kernel(
    const uint* __restrict__ hpk,        // packed frag-layout final h
    const float* __restrict__ external,
    const float* __restrict__ w_alpha,
    const float* __restrict__ w_sigma,
    float* __restrict__ mu,
    float* __restrict__ inv_sig,
    float* __restrict__ log_det)
{
    const int b = blockIdx.x;
    const int t = threadIdx.x;

    __shared__ float hs[HID];
    __shared__ float al[HIST];
    __shared__ float red[256];

    const int g = b >> 5, bl = b & 31;
    for (int k = t; k < HID; k += 256) {
        const uint wv = hpk[g * 16384 + h_widx(bl, k)];
        hs[k] = bf16_f32((unsigned short)(wv & 0xFFFF)) +
                bf16_f32((unsigned short)(wv >> 16));
    }
    __syncthreads();

    const float4* hs4 = (const float4*)hs;

    float lg[8];
    #pragma unroll
    for (int i = 0; i < 8; ++i) {
        const int e = t + 256 * i;
        const float4* wr = (const float4*)(w_alpha + (size_t)e * HID);
        float acc = 0.f;
        #pragma unroll 4
        for (int k = 0; k < HID / 4; ++k) {
            const float4 w4 = wr[k];
            const float4 h4 = hs4[k];
            acc += w4.x * h4.x + w4.y * h4.y + w4.z * h4.z + w4.w * h4.w;
        }
        lg[i] = acc;
    }

    float m = lg[0];
    #pragma unroll
    for (int i = 1; i < 8; ++i) m = fmaxf(m, lg[i]);
    red[t] = m;
    __syncthreads();
    for (int off = 128; off > 0; off >>= 1) {
        if (t < off) red[t] = fmaxf(red[t], red[t + off]);
        __syncthreads();
    }
    m = red[0];
    __syncthreads();

    float s = 0.f;
    #pragma unroll
    for (int i = 0; i < 8; ++i) {
        const float v = __expf(lg[i] - m);
        al[t + 256 * i] = v;
        s += v;
    }
    red[t] = s;
    __syncthreads();
    for (int off = 128; off > 0; off >>= 1) {
        if (t < off) red[t] += red[t + off];
        __syncthreads();
    }
    s = red[0];
    const float inv_s = 1.0f / s;
    __syncthreads();

    const int d = t;
    float acc_mu = 0.f;
    for (int e = 0; e < HIST; ++e) {
        acc_mu += al[e] * external[(size_t)e * DIN + d];
    }
    mu[(size_t)b * DIN + d] = acc_mu * inv_s;

    const float4* ws = (const float4*)(w_sigma + (size_t)d * HID);
    float sl = 0.f;
    #pragma unroll 4
    for (int k = 0; k < HID / 4; ++k) {
        const float4 w4 = ws[k];
        const float4 h4 = hs4[k];
        sl += w4.x * h4.x + w4.y * h4.y + w4.z * h4.z + w4.w * h4.w;
    }
    inv_sig[(size_t)b * DIN + d] = __expf(-sl);

    red[t] = sl;
    __syncthreads();
    for (int off = 128; off > 0; off >>= 1) {
        if (t < off) red[t] += red[t + off];
        __syncthreads();
    }
    if (t == 0) log_det[b] = red[0];
}

__global__ __launch_bounds__(256) void out_kernel(
    const float* __restrict__ x,
    const float* __restrict__ mu,
    const float* __restrict__ inv_sig,
    const float* __restrict__ log_det,
    float* __restrict__ out)
{
    const int s = blockIdx.x;
    const int b = threadIdx.x;
    const float4* xr = (const float4*)(x + ((size_t)s * BATCH + b) * DIN);
    const float4* mr = (const float4*)(mu + (size_t)b * DIN);
    const float4* ir = (const float4*)(inv_sig + (size_t)b * DIN);

    float maha = 0.f;
    #pragma unroll 8
    for (int k = 0; k < DIN / 4; ++k) {
        const float4 xv = xr[k];
        const float4 mv = mr[k];
        const float4 iv = ir[k];
        const float t0 = (xv.x - mv.x) * iv.x;
        const float t1 = (xv.y - mv.y) * iv.y;
        const float t2 = (xv.z - mv.z) * iv.z;
        const float t3 = (xv.w - mv.w) * iv.w;
        maha += t0 * t0 + t1 * t1 + t2 * t2 + t3 * t3;
    }
    const float LOG2PI = 1.8378770664093453f;
    out[(size_t)s * BATCH + b] = -0.5f * (maha + (float)DIN * LOG2PI) - log_det[b];
}

extern "C" void kernel_launch(void* const* d_in, const int* in_sizes, int n_in,
                              void* d_out, int out_size, void* d_ws, size_t ws_size,
                              hipStream_t stream)
{
    const float* x        = (const float*)d_in[0];
    const float* hidden   = (const float*)d_in[1];
    const float* external = (const float*)d_in[2];
    const float* w_ih     = (const float*)d_in[3];
    const float* w_hh     = (const float*)d_in[4];
    const float* w_alpha  = (const float*)d_in[5];
    const float* w_sigma  = (const float*)d_in[6];

    const int NH  = BATCH * HID;      // 131072
    const int NIH = 3 * HID * DIN;    // 393216
    const int NHH = 3 * HID * HID;    // 786432

    char* p = (char*)d_ws;
    int*  flags = (int*)p;            p += NBLK * 64;
    uint* hpA   = (uint*)p;           p += NH * 4;
    uint* hpB   = (uint*)p;           p += NH * 4;
    short* wih_hi = (short*)p;        p += NIH * 2;
    short* wih_lo = (short*)p;        p += NIH * 2;
    short* whh_hi = (short*)p;        p += NHH * 2;
    short* whh_lo = (short*)p;        p += NHH * 2;
    float* mu      = (float*)p;       p += BATCH * DIN * 4;
    float* inv_sig = (float*)p;       p += BATCH * DIN * 4;
    float* log_det = (float*)p;       p += BATCH * 4;

    (void)hipMemsetAsync(flags, 0, NBLK * 64, stream);

    split_kernel<<<(NIH + 255) / 256, 256, 0, stream>>>(w_ih, wih_hi, wih_lo, NIH);
    split_kernel<<<(NHH + 255) / 256, 256, 0, stream>>>(w_hh, whh_hi, whh_lo, NHH);
    pack_h_init<<<(NH + 255) / 256, 256, 0, stream>>>(hidden, hpA);

    gru_persistent<<<dim3(NBLK), dim3(512), 0, stream>>>(
        x, hidden, hpA, hpB, wih_hi, wih_lo, whh_hi, whh_lo, flags);
    // t=511 writes hpA -> final packed h in hpA

    attn_kernel<<<dim3(BATCH), dim3(256), 0, stream>>>(
        hpA, external, w_alpha, w_sigma, mu, inv_sig, log_det);

    out_kernel<<<dim3(SEQ), dim3(256), 0, stream>>>(
        x, mu, inv_sig, log_det, (float*)d_out);
}